// Round 1
// baseline (360.983 us; speedup 1.0000x reference)
//
#include <hip/hip_runtime.h>
#include <hip/hip_bf16.h>
#include <hip/hip_fp16.h>

typedef _Float16 f16x8 __attribute__((ext_vector_type(8)));
typedef _Float16 f16x4 __attribute__((ext_vector_type(4)));
typedef float    f32x4 __attribute__((ext_vector_type(4)));

#define KDIM   384
#define MBLK   64
#define PADK   392      // 384 + 8 f16 pad -> row stride 196 dwords, balanced banks
#define NEDGE  800000

// Pack W_lin (f32 [128][384], row-major) into MFMA B-fragment order, f16.
// Wp element idx = ((ks*8 + nt)*64 + lane)*8 + e  holds  W_lin[nt*16+(lane&15)][ks*32+(lane>>4)*8+e]
__global__ void pack_w_kernel(const float* __restrict__ W_lin,
                              _Float16* __restrict__ Wp) {
  int idx = blockIdx.x * 256 + threadIdx.x;   // exactly 12*8*64*8 = 49152 threads
  int e  = idx & 7;
  int l  = (idx >> 3) & 63;
  int nt = (idx >> 9) & 7;
  int ks = idx >> 12;
  int n  = (nt << 4) + (l & 15);
  int k  = (ks << 5) + ((l >> 4) << 3) + e;
  Wp[idx] = (_Float16)W_lin[n * KDIM + k];
}

__device__ __forceinline__ void cvt_store4(_Float16* dst, float4 v) {
  f16x4 a;
  a[0] = (_Float16)v.x; a[1] = (_Float16)v.y;
  a[2] = (_Float16)v.z; a[3] = (_Float16)v.w;
  *(f16x4*)dst = a;
}

__global__ __launch_bounds__(256, 3)
void embed_main_kernel(const int* __restrict__ x,
                       const float* __restrict__ rbf,
                       const int* __restrict__ gi,
                       const int* __restrict__ gj,
                       const float* __restrict__ resi_w,
                       const float* __restrict__ atom_w,
                       const float* __restrict__ W_rbf,
                       const float* __restrict__ b_rbf,
                       const float* __restrict__ b_lin,
                       const _Float16* __restrict__ Wp,
                       float* __restrict__ out) {
  __shared__ alignas(16) _Float16 hlds[MBLK][PADK];
  const int tid = threadIdx.x;
  const int e0  = blockIdx.x * MBLK;

  // ---- Phase 1a: embedding gather -> h[:, 0:256] (f16 in LDS)
  // 1024 tasks: (edge m 0..63) x (chunk c 0..15 of 16 elems)
  #pragma unroll
  for (int it = 0; it < 4; ++it) {
    int t   = tid + it * 256;
    int m   = t >> 4;
    int c   = t & 15;
    int e   = e0 + m;
    int seg = c >> 2;               // 0:resi(i) 1:atom(i) 2:resi(j) 3:atom(j)
    int off = (c & 3) << 4;
    int node = (seg < 2) ? gi[e] : gj[e];
    int sel  = x[(node << 1) + (seg & 1)];
    const float* src = ((seg & 1) ? (atom_w + sel * 64) : (resi_w + sel * 64)) + off;
    const float4* s4 = (const float4*)src;
    float4 v0 = s4[0], v1 = s4[1], v2 = s4[2], v3 = s4[3];
    _Float16* dst = &hlds[m][c << 4];
    cvt_store4(dst + 0,  v0);
    cvt_store4(dst + 4,  v1);
    cvt_store4(dst + 8,  v2);
    cvt_store4(dst + 12, v3);
  }

  // ---- Phase 1b: rbf_h = swish(rbf @ W_rbf^T + b_rbf) -> h[:, 256:384]
  {
    const int o = tid & 127;                 // output channel, fixed per thread
    const float* wr = W_rbf + o * 6;
    float w0 = wr[0], w1 = wr[1], w2 = wr[2], w3 = wr[3], w4 = wr[4], w5 = wr[5];
    float bb = b_rbf[o];
    int mb = tid >> 7;                       // 0 or 1
    #pragma unroll 4
    for (int it = 0; it < 32; ++it) {
      int m = mb + (it << 1);
      const float2* r2 = (const float2*)(rbf + (e0 + m) * 6);
      float2 ra = r2[0], rb = r2[1], rc = r2[2];
      float v = bb + ra.x * w0 + ra.y * w1 + rb.x * w2 + rb.y * w3 + rc.x * w4 + rc.y * w5;
      hlds[m][256 + o] = (_Float16)(v / (1.0f + __expf(-v)));
    }
  }
  __syncthreads();

  // ---- Phase 2: out-tile = h(64x384) @ W^T via mfma 16x16x32, K=384
  const int lane = tid & 63;
  const int wave = tid >> 6;
  const int g    = lane >> 4;
  const _Float16* arow = &hlds[(wave << 4) + (lane & 15)][g << 3];
  const f16x8* wp = ((const f16x8*)Wp) + lane;

  f32x4 acc[8];
  #pragma unroll
  for (int nt = 0; nt < 8; ++nt) acc[nt] = (f32x4){0.f, 0.f, 0.f, 0.f};

  for (int ks = 0; ks < 12; ++ks) {
    f16x8 a = *(const f16x8*)(arow + ks * 32);
    #pragma unroll
    for (int nt = 0; nt < 8; ++nt) {
      f16x8 b = wp[(ks * 8 + nt) * 64];
      acc[nt] = __builtin_amdgcn_mfma_f32_16x16x32_f16(a, b, acc[nt], 0, 0, 0);
    }
  }

  // ---- Epilogue: +bias, swish, store f32 (D: col = lane&15, row = 4*(lane>>4)+reg)
  const int ebase = e0 + (wave << 4) + (g << 2);
  const int col0  = lane & 15;
  #pragma unroll
  for (int nt = 0; nt < 8; ++nt) {
    int col  = (nt << 4) + col0;
    float bl = b_lin[col];
    #pragma unroll
    for (int r = 0; r < 4; ++r) {
      float v  = acc[nt][r] + bl;
      float sw = v / (1.0f + __expf(-v));
      out[(ebase + r) * 128 + col] = sw;
    }
  }
}

extern "C" void kernel_launch(void* const* d_in, const int* in_sizes, int n_in,
                              void* d_out, int out_size, void* d_ws, size_t ws_size,
                              hipStream_t stream) {
  const int*   x      = (const int*)d_in[0];
  const float* rbf    = (const float*)d_in[1];
  const int*   gi     = (const int*)d_in[2];
  const int*   gj     = (const int*)d_in[3];
  const float* resi_w = (const float*)d_in[4];
  const float* atom_w = (const float*)d_in[5];
  const float* W_rbf  = (const float*)d_in[6];
  const float* b_rbf  = (const float*)d_in[7];
  const float* W_lin  = (const float*)d_in[8];
  const float* b_lin  = (const float*)d_in[9];
  float* out = (float*)d_out;
  _Float16* Wp = (_Float16*)d_ws;   // 49152 * 2B = 96 KB

  hipLaunchKernelGGL(pack_w_kernel, dim3(192), dim3(256), 0, stream, W_lin, Wp);
  hipLaunchKernelGGL(embed_main_kernel, dim3(NEDGE / MBLK), dim3(256), 0, stream,
                     x, rbf, gi, gj, resi_w, atom_w, W_rbf, b_rbf, b_lin, Wp, out);
}

// Round 3
// 205.541 us; speedup vs baseline: 1.7563x; 1.7563x over previous
//
#include <hip/hip_runtime.h>
#include <hip/hip_bf16.h>
#include <hip/hip_fp16.h>

typedef _Float16 f16x8 __attribute__((ext_vector_type(8)));
typedef __fp16   h16x2 __attribute__((ext_vector_type(2)));
typedef float    f32x4 __attribute__((ext_vector_type(4)));

#define KDIM     384
#define MBLK     64
#define PADK     392      // 384 + 8 f16 pad -> row stride 196 dwords (196 mod 32 = 4)
#define NEDGE    800000
#define WP_ELEMS 49152    // 12*8*64*8

__device__ __forceinline__ float fast_swish(float v) {
  return v * __builtin_amdgcn_rcpf(1.0f + __expf(-v));
}

__device__ __forceinline__ void pack8(_Float16* dst, float4 a, float4 b) {
  union { h16x2 h[4]; f16x8 v; } u;
  u.h[0] = __builtin_amdgcn_cvt_pkrtz(a.x, a.y);
  u.h[1] = __builtin_amdgcn_cvt_pkrtz(a.z, a.w);
  u.h[2] = __builtin_amdgcn_cvt_pkrtz(b.x, b.y);
  u.h[3] = __builtin_amdgcn_cvt_pkrtz(b.z, b.w);
  *(f16x8*)dst = u.v;
}

// Pack W_lin (f32 [128][384]) into main-GEMM B-fragment order (f16) and
// W_rbf (f32 [128][6]) into rbf B-fragment order (f16, K padded 6->32 with 0).
// Wp[((ks*8+nt)*64 + l)*8 + e] = W_lin[nt*16+(l&15)][ks*32+(l>>4)*8+e]
// Wrp[(nt*64 + l)*8 + e]       = k<6 ? W_rbf[nt*16+(l&15)][k] : 0,  k=(l>>4)*8+e
__global__ void pack_w_kernel(const float* __restrict__ W_lin,
                              const float* __restrict__ W_rbf,
                              _Float16* __restrict__ Wp,
                              _Float16* __restrict__ Wrp) {
  int idx = blockIdx.x * 256 + threadIdx.x;
  if (idx < WP_ELEMS) {
    int e  = idx & 7;
    int l  = (idx >> 3) & 63;
    int nt = (idx >> 9) & 7;
    int ks = idx >> 12;
    int n  = (nt << 4) + (l & 15);
    int k  = (ks << 5) + ((l >> 4) << 3) + e;
    Wp[idx] = (_Float16)W_lin[n * KDIM + k];
  } else if (idx < WP_ELEMS + 4096) {
    int idx2 = idx - WP_ELEMS;
    int e  = idx2 & 7;
    int l  = (idx2 >> 3) & 63;
    int nt = idx2 >> 9;
    int k  = ((l >> 4) << 3) + e;
    float v = (k < 6) ? W_rbf[(nt * 16 + (l & 15)) * 6 + k] : 0.0f;
    Wrp[idx2] = (_Float16)v;
  }
}

__global__ __launch_bounds__(256, 3)
void embed_main_kernel(const int* __restrict__ x,
                       const float* __restrict__ rbf,
                       const int* __restrict__ gi,
                       const int* __restrict__ gj,
                       const float* __restrict__ resi_w,
                       const float* __restrict__ atom_w,
                       const float* __restrict__ b_rbf,
                       const float* __restrict__ b_lin,
                       const _Float16* __restrict__ Wp,
                       const _Float16* __restrict__ Wrp,
                       float* __restrict__ out) {
  __shared__ alignas(16) _Float16 hlds[MBLK][PADK];
  const int tid  = threadIdx.x;
  const int e0   = blockIdx.x * MBLK;
  const int lane = tid & 63;
  const int wave = tid >> 6;
  const int g    = lane >> 4;
  const int c    = lane & 15;

  // ---- Phase 1a (part 1): issue all index chains early
  const int cc  = tid & 15;          // chunk 0..15 (16 f16 each)
  const int seg = cc >> 2;           // 0 resi(i) 1 atom(i) 2 resi(j) 3 atom(j)
  const int off = (cc & 3) << 4;
  const int* __restrict__ gsel = (seg < 2) ? gi : gj;
  const float* __restrict__ tbl = (seg & 1) ? atom_w : resi_w;
  const int m0 = tid >> 4;           // 0..15
  int sel_[4];
  #pragma unroll
  for (int it = 0; it < 4; ++it) {
    int node = gsel[e0 + m0 + it * 16];
    sel_[it] = x[(node << 1) + (seg & 1)];
  }

  // ---- Phase 1b: rbf_h = swish(rbf @ W_rbf^T + b_rbf) via MFMA (K=32, 6 used)
  {
    f16x8 ra = {0, 0, 0, 0, 0, 0, 0, 0};
    if (g == 0) {
      const float* rp = rbf + (size_t)(e0 + wave * 16 + c) * 6;
      ra[0] = (_Float16)rp[0]; ra[1] = (_Float16)rp[1]; ra[2] = (_Float16)rp[2];
      ra[3] = (_Float16)rp[3]; ra[4] = (_Float16)rp[4]; ra[5] = (_Float16)rp[5];
    }
    const f16x8* wrb = (const f16x8*)Wrp + lane;
    #pragma unroll
    for (int nt = 0; nt < 8; ++nt) {
      f16x8 rb = wrb[nt * 64];
      f32x4 d = __builtin_amdgcn_mfma_f32_16x16x32_f16(ra, rb,
                  (f32x4){0.f, 0.f, 0.f, 0.f}, 0, 0, 0);
      float bb = b_rbf[nt * 16 + c];
      #pragma unroll
      for (int r = 0; r < 4; ++r) {
        float vv = d[r] + bb;
        hlds[wave * 16 + 4 * g + r][256 + nt * 16 + c] = (_Float16)fast_swish(vv);
      }
    }
  }

  // ---- Phase 1a (part 2): embedding rows -> hlds[:, 0:256]
  #pragma unroll
  for (int it = 0; it < 4; ++it) {
    int m = m0 + it * 16;
    const float4* s4 = (const float4*)(tbl + sel_[it] * 64 + off);
    float4 v0 = s4[0], v1 = s4[1], v2 = s4[2], v3 = s4[3];
    _Float16* dst = &hlds[m][cc << 4];
    pack8(dst,     v0, v1);
    pack8(dst + 8, v2, v3);
  }
  __syncthreads();

  // ---- Phase 2: 64x384 @ 384x128. Wave w: all 4 M-tiles x N-tiles {2w, 2w+1}
  const _Float16* abase = &hlds[c][g << 3];
  const f16x8* wpB = (const f16x8*)Wp + (wave * 2) * 64 + lane;

  f32x4 acc[4][2];
  #pragma unroll
  for (int mt = 0; mt < 4; ++mt) {
    acc[mt][0] = (f32x4){0.f, 0.f, 0.f, 0.f};
    acc[mt][1] = (f32x4){0.f, 0.f, 0.f, 0.f};
  }

  #pragma unroll
  for (int ks = 0; ks < 12; ++ks) {
    f16x8 b0 = wpB[ks * 512];
    f16x8 b1 = wpB[ks * 512 + 64];
    #pragma unroll
    for (int mt = 0; mt < 4; ++mt) {
      f16x8 a = *(const f16x8*)(abase + mt * 16 * PADK + ks * 32);
      acc[mt][0] = __builtin_amdgcn_mfma_f32_16x16x32_f16(a, b0, acc[mt][0], 0, 0, 0);
      acc[mt][1] = __builtin_amdgcn_mfma_f32_16x16x32_f16(a, b1, acc[mt][1], 0, 0, 0);
    }
  }

  // ---- Epilogue: +bias, swish, store f32. D: col=lane&15, row=4*(lane>>4)+r
  const int col0 = wave * 32 + c;
  const float bl0 = b_lin[col0];
  const float bl1 = b_lin[col0 + 16];
  #pragma unroll
  for (int mt = 0; mt < 4; ++mt) {
    const int erow = e0 + mt * 16 + 4 * g;
    #pragma unroll
    for (int r = 0; r < 4; ++r) {
      float* orow = out + (size_t)(erow + r) * 128;
      orow[col0]      = fast_swish(acc[mt][0][r] + bl0);
      orow[col0 + 16] = fast_swish(acc[mt][1][r] + bl1);
    }
  }
}

extern "C" void kernel_launch(void* const* d_in, const int* in_sizes, int n_in,
                              void* d_out, int out_size, void* d_ws, size_t ws_size,
                              hipStream_t stream) {
  const int*   x      = (const int*)d_in[0];
  const float* rbf    = (const float*)d_in[1];
  const int*   gi     = (const int*)d_in[2];
  const int*   gj     = (const int*)d_in[3];
  const float* resi_w = (const float*)d_in[4];
  const float* atom_w = (const float*)d_in[5];
  const float* W_rbf  = (const float*)d_in[6];
  const float* b_rbf  = (const float*)d_in[7];
  const float* W_lin  = (const float*)d_in[8];
  const float* b_lin  = (const float*)d_in[9];
  float* out = (float*)d_out;
  _Float16* Wp  = (_Float16*)d_ws;                 // 96 KB
  _Float16* Wrp = (_Float16*)d_ws + WP_ELEMS;      // + 8 KB

  hipLaunchKernelGGL(pack_w_kernel, dim3(208), dim3(256), 0, stream,
                     W_lin, W_rbf, Wp, Wrp);
  hipLaunchKernelGGL(embed_main_kernel, dim3(NEDGE / MBLK), dim3(256), 0, stream,
                     x, rbf, gi, gj, resi_w, atom_w, b_rbf, b_lin, Wp, Wrp, out);
}